// Round 2
// baseline (1920.098 us; speedup 1.0000x reference)
//
#include <hip/hip_runtime.h>
#include <hip/hip_bf16.h>

static constexpr int DIN = 128;
static constexpr int HID = 64;

// ---- dual-dtype load: m=1 -> fp32, m=0 -> bf16 ----
__device__ __forceinline__ float ldm(const void* p, long long i, int m) {
    return m ? ((const float*)p)[i]
             : __bfloat162float(((const __hip_bfloat16*)p)[i]);
}

// ---- dtype probe: decide fp32 vs bf16 from bit patterns of Wl1_dg ----
// bf16 data: bits[14:7] of each 32b word = exponent of a ~N(0,1/sqrt(128)) bf16
//            value -> in [110,130] with p~0.999.
// fp32 data: bits[14:7] = mid-mantissa bits -> uniform -> p~0.08.
__global__ void probe_kernel(const unsigned* __restrict__ w, int* __restrict__ flag) {
    if (threadIdx.x == 0 && blockIdx.x == 0) {
        int hits = 0;
        for (int i = 0; i < 64; ++i) {
            unsigned ex = (w[i] >> 7) & 0xffu;
            if (ex >= 110u && ex <= 130u) hits++;
        }
        *flag = (hits >= 32) ? 0 : 1;   // 0 = bf16, 1 = fp32
    }
}

// ---- projection: out[n,j] = sum_k X[n,k] * W[k,j]; out fp32 [N,64] ----
template<int K>
__global__ void proj_kernel(const void* __restrict__ x, const void* __restrict__ W,
                            float* __restrict__ out, int N,
                            const int* __restrict__ flag, int xmode /*2=flag,1=f32*/) {
    __shared__ float sW[K * 64];
    const int m = *flag;
    const int xm = (xmode == 2) ? m : 1;
    for (int i = threadIdx.x; i < K * 64; i += blockDim.x) sW[i] = ldm(W, i, m);
    __syncthreads();
    const int j = threadIdx.x & 63;
    const int base = blockIdx.x * 64;
    for (int t = threadIdx.x >> 6; t < 64; t += (blockDim.x >> 6)) {
        int n = base + t;
        if (n >= N) break;
        float s = 0.0f;
        #pragma unroll 8
        for (int k = 0; k < K; ++k)
            s += ldm(x, (long long)n * K + k, xm) * sW[k * 64 + j];
        out[(long long)n * 64 + j] = s;
    }
}

// ---- scatter: acc[dst[e], k] += rows[src[e], k], rows are fp32 [*,64] ----
__global__ void scatter_kernel(const float* __restrict__ rows,
                               const int* __restrict__ src,
                               const int* __restrict__ dst,
                               float* __restrict__ acc,
                               float* __restrict__ cnt, int nE) {
    long long idx = (long long)blockIdx.x * blockDim.x + threadIdx.x;
    if (idx >= (long long)nE * 64) return;
    int e = (int)(idx >> 6);
    int k = (int)(idx & 63);
    int d = dst[e];
    float v = rows[(long long)src[e] * 64 + k];
    atomicAdd(acc + (long long)d * 64 + k, v);
    if (cnt != nullptr && k == 0) atomicAdd(cnt + d, 1.0f);
}

// ---- combine: out[n,j] = acc[n,j]/max(cnt,1) + sum_k X2[n,k]*Wr[k,j] + b[j] ----
// omode: 1 -> fp32 out (may alias acc), 2 -> follow flag (final d_out)
template<int K>
__global__ void combine_kernel(const float* __restrict__ acc, const float* __restrict__ cnt,
                               const void* __restrict__ x2, int x2mode,
                               const void* __restrict__ Wr, const void* __restrict__ bl,
                               void* __restrict__ out, long long out_off, int omode,
                               int N, const int* __restrict__ flag) {
    __shared__ float sW[K * 64];
    const int m = *flag;
    const int xm = (x2mode == 2) ? m : 1;
    const int om = (omode == 2) ? m : 1;
    for (int i = threadIdx.x; i < K * 64; i += blockDim.x) sW[i] = ldm(Wr, i, m);
    __syncthreads();
    const int j = threadIdx.x & 63;
    const float b = ldm(bl, j, m);
    const int base = blockIdx.x * 64;
    for (int t = threadIdx.x >> 6; t < 64; t += (blockDim.x >> 6)) {
        int n = base + t;
        if (n >= N) break;
        float inv = 1.0f / fmaxf(cnt[n], 1.0f);
        float s = 0.0f;
        #pragma unroll 8
        for (int k = 0; k < K; ++k)
            s += ldm(x2, (long long)n * K + k, xm) * sW[k * 64 + j];
        float v = acc[(long long)n * 64 + j] * inv + s + b;
        long long o = out_off + (long long)n * 64 + j;
        if (om) ((float*)out)[o] = v;
        else    ((__hip_bfloat16*)out)[o] = __float2bfloat16(v);
    }
}

extern "C" void kernel_launch(void* const* d_in, const int* in_sizes, int n_in,
                              void* d_out, int out_size, void* d_ws, size_t ws_size,
                              hipStream_t stream) {
    const void* x_d    = d_in[0];
    const void* x_g    = d_in[1];
    const int* src_dg  = (const int*)d_in[2];
    const int* dst_dg  = (const int*)d_in[3];
    const int* src_gd  = (const int*)d_in[4];
    const int* dst_gd  = (const int*)d_in[5];
    const void* Wl1_dg = d_in[6];
    const void* bl1_dg = d_in[7];
    const void* Wr1_dg = d_in[8];
    const void* Wl1_gd = d_in[9];
    const void* bl1_gd = d_in[10];
    const void* Wr1_gd = d_in[11];
    const void* Wl2_dg = d_in[12];
    const void* bl2_dg = d_in[13];
    const void* Wr2_dg = d_in[14];
    const void* Wl2_gd = d_in[15];
    const void* bl2_gd = d_in[16];
    const void* Wr2_gd = d_in[17];

    const int nd = in_sizes[0] / DIN;   // 50000
    const int ng = in_sizes[1] / DIN;   // 100000
    const int ne = in_sizes[2];         // 600000

    // ---- workspace layout (fp32), total ~77.4 MB ----
    int*   flag = (int*)d_ws;
    float* base = (float*)d_ws;
    float* cntG = base + 64;                       // [ng]
    float* cntD = cntG + (size_t)ng;               // [nd]
    float* g1   = cntD + (size_t)nd;               // [ng,64] acc then output (in place)
    float* d1   = g1 + (size_t)ng * HID;           // [nd,64] acc then output (in place)
    float* D2A  = d1 + (size_t)nd * HID;           // [nd,64]; (d1|D2A) contiguous = G2A [ng,64]
    float* P    = D2A + (size_t)nd * HID;          // [ng,64] projection scratch
    float* G2A  = d1;                              // aliases d1+D2A after both are dead

    const int block = 256;
    const int gN_g  = (ng + 63) / 64;              // node-parallel grids
    const int gN_d  = (nd + 63) / 64;
    const int gE    = (int)(((long long)ne * 64 + block - 1) / block);

    // 0) dtype probe
    probe_kernel<<<1, 64, 0, stream>>>((const unsigned*)Wl1_dg, flag);

    // 1) zero cntG,cntD,g1,d1 (contiguous)
    hipMemsetAsync(cntG, 0, ((size_t)(ng + nd) + (size_t)(ng + nd) * HID) * sizeof(float), stream);

    // ---- layer 1, relation d->g : g1 ----
    proj_kernel<DIN><<<gN_d, block, 0, stream>>>(x_d, Wl1_dg, P, nd, flag, 2);
    scatter_kernel<<<gE, block, 0, stream>>>(P, src_dg, dst_dg, g1, cntG, ne);
    combine_kernel<DIN><<<gN_g, block, 0, stream>>>(g1, cntG, x_g, 2, Wr1_dg, bl1_dg,
                                                    (void*)g1, 0, 1, ng, flag);

    // ---- layer 1, relation g->d : d1 ----
    proj_kernel<DIN><<<gN_g, block, 0, stream>>>(x_g, Wl1_gd, P, ng, flag, 2);
    scatter_kernel<<<gE, block, 0, stream>>>(P, src_gd, dst_gd, d1, cntD, ne);
    combine_kernel<DIN><<<gN_d, block, 0, stream>>>(d1, cntD, x_d, 2, Wr1_gd, bl1_gd,
                                                    (void*)d1, 0, 1, nd, flag);

    // ---- layer 2, relation g->d : d2 (written to d_out offset 0) ----
    proj_kernel<HID><<<gN_g, block, 0, stream>>>(g1, Wl2_gd, P, ng, flag, 1);
    hipMemsetAsync(D2A, 0, (size_t)nd * HID * sizeof(float), stream);
    scatter_kernel<<<gE, block, 0, stream>>>(P, src_gd, dst_gd, D2A, nullptr, ne);
    // project d1 BEFORE d1's region is recycled; P is dead after the scatter above
    proj_kernel<HID><<<gN_d, block, 0, stream>>>(d1, Wl2_dg, P, nd, flag, 1);
    combine_kernel<HID><<<gN_d, block, 0, stream>>>(D2A, cntD, d1, 1, Wr2_gd, bl2_gd,
                                                    d_out, 0, 2, nd, flag);

    // ---- layer 2, relation d->g : g2 (written to d_out offset nd*64) ----
    // d1 and D2A are both dead now; their contiguous span becomes G2A [ng,64]
    hipMemsetAsync(G2A, 0, (size_t)ng * HID * sizeof(float), stream);
    scatter_kernel<<<gE, block, 0, stream>>>(P, src_dg, dst_dg, G2A, nullptr, ne);
    combine_kernel<HID><<<gN_g, block, 0, stream>>>(G2A, cntG, g1, 1, Wr2_dg, bl2_dg,
                                                    d_out, (long long)nd * HID, 2, ng, flag);
}